// Round 1
// baseline (22696.561 us; speedup 1.0000x reference)
//
#include <hip/hip_runtime.h>
#include <hip/hip_bf16.h>

typedef __attribute__((ext_vector_type(8))) short bf16x8;
typedef __attribute__((ext_vector_type(4))) float f32x4;

__device__ __forceinline__ short f2bf(float f) {
  __hip_bfloat16 h = __float2bfloat16(f);
  return *reinterpret_cast<short*>(&h);
}
__device__ __forceinline__ float bf2f(short s) {
  __hip_bfloat16 h;
  *reinterpret_cast<short*>(&h) = s;
  return __bfloat162float(h);
}
__device__ __forceinline__ float sigm(float x) { return 1.f / (1.f + __expf(-x)); }

// ---------------- precompute: weight swizzles + emb convert ----------------
// Wswz element offset for (layer l, nfrag nf in [0,128), kstep ks in [0,32), lane, e):
//   ((l*128 + nf)*32 + ks)*512 + lane*8 + e   ==  W[l][nf*16 + (lane&15)][ks*32 + (lane>>4)*8 + e]
__global__ void swz_w_kernel(const float* __restrict__ W, short* __restrict__ dst) {
  int uid = blockIdx.x * blockDim.x + threadIdx.x;   // 524288 16B-units
  int l    = uid >> 18;
  int rem  = uid & 262143;
  int nf   = rem >> 11;
  int ks   = (rem >> 6) & 31;
  int lane = rem & 63;
  int row  = nf * 16 + (lane & 15);
  int k0   = ks * 32 + (lane >> 4) * 8;
  const float* src = W + ((size_t)(l * 2048 + row)) * 1024 + k0;
  short v[8];
#pragma unroll
  for (int e = 0; e < 8; ++e) v[e] = f2bf(src[e]);
  *reinterpret_cast<int4*>(dst + (size_t)uid * 8) = *reinterpret_cast<int4*>(v);
}

// pWswz: (nf in [0,16), ks in [0,16)): ((nf*16+ks)*512 + lane*8 + e) == pW[nf*16+(lane&15)][ks*32+(lane>>4)*8+e]
__global__ void swz_pw_kernel(const float* __restrict__ pW, short* __restrict__ dst) {
  int uid = blockIdx.x * blockDim.x + threadIdx.x;   // 16384 units
  int nf   = uid >> 10;
  int ks   = (uid >> 6) & 15;
  int lane = uid & 63;
  int row  = nf * 16 + (lane & 15);
  int k0   = ks * 32 + (lane >> 4) * 8;
  const float* src = pW + row * 512 + k0;
  short v[8];
#pragma unroll
  for (int e = 0; e < 8; ++e) v[e] = f2bf(src[e]);
  *reinterpret_cast<int4*>(dst + (size_t)uid * 8) = *reinterpret_cast<int4*>(v);
}

__global__ void conv_emb_kernel(const float* __restrict__ src, short* __restrict__ dst, int n) {
  int i = blockIdx.x * blockDim.x + threadIdx.x;
  if (i < n) dst[i] = f2bf(src[i]);
}

// ---------------- projection (LayerNorm + GEMM [32 x 256] K=512) ----------------
__device__ __forceinline__ void proj_body(char* smem, int pid,
    const short* __restrict__ h1p, const short* __restrict__ pWswz,
    const float* __restrict__ lng, const float* __restrict__ lnb,
    const float* __restrict__ pb, float* __restrict__ out, int tout)
{
  const int tid = threadIdx.x;
  const int prow0 = pid * 32;
  // stage 32 h1 rows (bf16, raw) into LDS [32][512]
  for (int i = tid; i < 2048; i += 512) {
    int row = i >> 6, seg = i & 63;
    *reinterpret_cast<int4*>(smem + row * 1024 + seg * 16) =
        *reinterpret_cast<const int4*>(h1p + (prow0 + row) * 512 + seg * 8);
  }
  __syncthreads();
  {
    // LayerNorm: 16 threads per row, 32 elems each
    int row = tid >> 4, j = tid & 15;
    const short* hr = reinterpret_cast<const short*>(smem) + row * 512;
    float s1 = 0.f, s2 = 0.f;
#pragma unroll
    for (int kk = 0; kk < 32; ++kk) {
      float v = bf2f(hr[j * 32 + kk]);
      s1 += v; s2 += v * v;
    }
#pragma unroll
    for (int d = 1; d < 16; d <<= 1) { s1 += __shfl_xor(s1, d, 64); s2 += __shfl_xor(s2, d, 64); }
    float mu = s1 * (1.f / 512.f);
    float rs = rsqrtf(s2 * (1.f / 512.f) - mu * mu + 1e-5f);
    char* zn = smem + 32768;
#pragma unroll
    for (int kk = 0; kk < 32; ++kk) {
      int k = j * 32 + kk;
      float v = bf2f(hr[k]);
      float nv = (v - mu) * rs * lng[k] + lnb[k];
      *reinterpret_cast<short*>(zn + row * 1024 + ((k * 2) ^ ((row & 7) << 4))) = f2bf(nv);
    }
  }
  __syncthreads();
  const int w = tid >> 6, lane = tid & 63, l15 = lane & 15, lq = lane >> 4;
  const char* zn = smem + 32768;
  const char* ap = zn + l15 * 1024;
  const int swz = (l15 & 7) << 4;
  const short* bp0 = pWswz + (size_t)(w * 2) * 8192 + lane * 8;
  const short* bp1 = bp0 + 8192;
  f32x4 acc[2][2] = {};
#pragma unroll 4
  for (int ks = 0; ks < 16; ++ks) {
    int kb = ks * 64 + lq * 16;
    bf16x8 a0 = *reinterpret_cast<const bf16x8*>(ap + (kb ^ swz));
    bf16x8 a1 = *reinterpret_cast<const bf16x8*>(ap + 16 * 1024 + (kb ^ swz));
    bf16x8 b0 = *reinterpret_cast<const bf16x8*>(bp0 + ks * 512);
    bf16x8 b1 = *reinterpret_cast<const bf16x8*>(bp1 + ks * 512);
    acc[0][0] = __builtin_amdgcn_mfma_f32_16x16x32_bf16(a0, b0, acc[0][0], 0, 0, 0);
    acc[1][0] = __builtin_amdgcn_mfma_f32_16x16x32_bf16(a1, b0, acc[1][0], 0, 0, 0);
    acc[0][1] = __builtin_amdgcn_mfma_f32_16x16x32_bf16(a0, b1, acc[0][1], 0, 0, 0);
    acc[1][1] = __builtin_amdgcn_mfma_f32_16x16x32_bf16(a1, b1, acc[1][1], 0, 0, 0);
  }
#pragma unroll
  for (int mf = 0; mf < 2; ++mf)
#pragma unroll
    for (int nfi = 0; nfi < 2; ++nfi)
#pragma unroll
      for (int r = 0; r < 4; ++r) {
        int vcol = (w * 2 + nfi) * 16 + l15;
        int rowg = prow0 + mf * 16 + lq * 4 + r;
        out[(size_t)rowg * 262144 + (size_t)tout * 256 + vcol] = acc[mf][nfi][r] + pb[vcol];
      }
}

// ---------------- one LSTM layer step ----------------
// Grid (LAYER==0): 36 blocks — 32 GEMM blocks + 4 projection blocks (project step t-1).
// Grid (LAYER==1): 32 blocks.
// GEMM block bid<32: mhalf=bid&1 (64 batch rows), colgrp=bid>>1 (32 h-cols; gate cols g*512+colgrp*32).
template<int LAYER>
__global__ __launch_bounds__(512) void step_kernel(
    const short* __restrict__ Wswz,     // this layer's swizzled weights
    const float* __restrict__ bias,     // this layer's bias [2048]
    const short* __restrict__ zsrc0,    // L0: embbf table [256][512]; L1: h0[cur]
    const int* __restrict__ x, int t,
    const short* __restrict__ zsrc1,    // h_prev of this layer [128][512]
    float* __restrict__ c,              // [128][512] f32
    short* __restrict__ hout,           // [128][512] bf16
    const short* __restrict__ h1prev,   // for projection (L0 only)
    const short* __restrict__ pWswz,
    const float* __restrict__ lng, const float* __restrict__ lnb,
    const float* __restrict__ pb, float* __restrict__ out)
{
  __shared__ __align__(16) char smem[131328];
  const int bid = blockIdx.x;
  const int tid = threadIdx.x;

  if (LAYER == 0 && bid >= 32) {
    if (t == 0) return;
    proj_body(smem, bid - 32, h1prev, pWswz, lng, lnb, pb, out, t - 1);
    return;
  }

  const int mhalf = bid & 1;
  const int colgrp = bid >> 1;
  const int m0 = mhalf * 64;
  int* xids = reinterpret_cast<int*>(smem + 131072);

  if (LAYER == 0) {
    if (tid < 64) xids[tid] = x[(m0 + tid) * 1024 + t];
    __syncthreads();
  }
  // stage z = [x-part | h-part] into LDS: 64 rows x 1024 k, bf16, XOR-swizzled
  for (int i = tid; i < 8192; i += 512) {
    int row = i >> 7;
    int seg = i & 127;
    const short* src;
    if (seg < 64) {
      int base = (LAYER == 0) ? xids[row] * 512 : (m0 + row) * 512;
      src = zsrc0 + base + seg * 8;
    } else {
      src = zsrc1 + (m0 + row) * 512 + (seg - 64) * 8;
    }
    int4 v = *reinterpret_cast<const int4*>(src);
    *reinterpret_cast<int4*>(smem + row * 2048 + ((seg * 16) ^ ((row & 7) << 4))) = v;
  }
  __syncthreads();

  const int w = tid >> 6, lane = tid & 63;
  const int g = w & 3, mg = (w >> 2) * 32;   // gate type, row-half within tile
  const int l15 = lane & 15, lq = lane >> 4;
  const int swz = (l15 & 7) << 4;

  const char* aptr0 = smem + (mg + l15) * 2048;
  const int nfbase = g * 32 + colgrp * 2;
  const short* bptr0 = Wswz + (size_t)nfbase * 16384 + lane * 8;

  f32x4 acc[2][2] = {};
#pragma unroll 4
  for (int ks = 0; ks < 32; ++ks) {
    int kb = ks * 64 + lq * 16;
    bf16x8 a0 = *reinterpret_cast<const bf16x8*>(aptr0 + (kb ^ swz));
    bf16x8 a1 = *reinterpret_cast<const bf16x8*>(aptr0 + 16 * 2048 + (kb ^ swz));
    bf16x8 b0 = *reinterpret_cast<const bf16x8*>(bptr0 + ks * 512);
    bf16x8 b1 = *reinterpret_cast<const bf16x8*>(bptr0 + 16384 + ks * 512);
    acc[0][0] = __builtin_amdgcn_mfma_f32_16x16x32_bf16(a0, b0, acc[0][0], 0, 0, 0);
    acc[1][0] = __builtin_amdgcn_mfma_f32_16x16x32_bf16(a1, b0, acc[1][0], 0, 0, 0);
    acc[0][1] = __builtin_amdgcn_mfma_f32_16x16x32_bf16(a0, b1, acc[0][1], 0, 0, 0);
    acc[1][1] = __builtin_amdgcn_mfma_f32_16x16x32_bf16(a1, b1, acc[1][1], 0, 0, 0);
  }
  __syncthreads();
  // gates to LDS [4][64][32] f32
  float* gl = reinterpret_cast<float*>(smem);
#pragma unroll
  for (int mf = 0; mf < 2; ++mf)
#pragma unroll
    for (int nfi = 0; nfi < 2; ++nfi)
#pragma unroll
      for (int r = 0; r < 4; ++r)
        gl[(g * 64 + mg + mf * 16 + lq * 4 + r) * 32 + nfi * 16 + l15] = acc[mf][nfi][r];
  __syncthreads();

  const int cbase = colgrp * 32;
  for (int i = tid; i < 2048; i += 512) {
    int col = i & 31, row = i >> 5;
    float iv = sigm(gl[(0 * 64 + row) * 32 + col] + bias[cbase + col]);
    float fv = sigm(gl[(1 * 64 + row) * 32 + col] + bias[512 + cbase + col]);
    float ov = sigm(gl[(2 * 64 + row) * 32 + col] + bias[1024 + cbase + col]);
    float gv = tanhf(gl[(3 * 64 + row) * 32 + col] + bias[1536 + cbase + col]);
    size_t idx = (size_t)(m0 + row) * 512 + cbase + col;
    float cn = fv * c[idx] + iv * gv;
    c[idx] = cn;
    hout[idx] = f2bf(ov * tanhf(cn));
  }
}

// final projection for t=1023
__global__ __launch_bounds__(512) void proj_last_kernel(
    const short* __restrict__ h1last, const short* __restrict__ pWswz,
    const float* __restrict__ lng, const float* __restrict__ lnb,
    const float* __restrict__ pb, float* __restrict__ out)
{
  __shared__ __align__(16) char smem[65536];
  proj_body(smem, blockIdx.x, h1last, pWswz, lng, lnb, pb, out, 1023);
}

extern "C" void kernel_launch(void* const* d_in, const int* in_sizes, int n_in,
                              void* d_out, int out_size, void* d_ws, size_t ws_size,
                              hipStream_t stream) {
  const int*   x    = (const int*)d_in[0];
  const float* emb  = (const float*)d_in[1];
  const float* W    = (const float*)d_in[2];
  const float* bias = (const float*)d_in[3];
  const float* lng  = (const float*)d_in[4];
  const float* lnb  = (const float*)d_in[5];
  const float* pW   = (const float*)d_in[6];
  const float* pb   = (const float*)d_in[7];
  float* out = (float*)d_out;

  char* ws = (char*)d_ws;
  short* Wswz  = (short*)(ws);                 // 8,388,608 B  (2 layers bf16 swizzled)
  short* pWswz = (short*)(ws + 8388608);       //   262,144 B
  short* embbf = (short*)(ws + 8650752);       //   262,144 B
  short* h0buf = (short*)(ws + 8912896);       //   262,144 B  [2][128][512] bf16
  short* h1buf = (short*)(ws + 9175040);       //   262,144 B
  float* c0    = (float*)(ws + 9437184);       //   262,144 B
  float* c1    = (float*)(ws + 9699328);       //   262,144 B

  // zero LSTM state (h buffers + cell state) — required every call (ws is poisoned)
  hipMemsetAsync(ws + 8912896, 0, 1048576, stream);
  swz_w_kernel<<<dim3(2048), dim3(256), 0, stream>>>(W, Wswz);
  swz_pw_kernel<<<dim3(64), dim3(256), 0, stream>>>(pW, pWswz);
  conv_emb_kernel<<<dim3(512), dim3(256), 0, stream>>>(emb, embbf, 131072);

  for (int t = 0; t < 1024; ++t) {
    int cur = t & 1, prev = cur ^ 1;
    step_kernel<0><<<dim3(36), dim3(512), 0, stream>>>(
        Wswz, bias, embbf, x, t, h0buf + prev * 65536, c0, h0buf + cur * 65536,
        h1buf + prev * 65536, pWswz, lng, lnb, pb, out);
    step_kernel<1><<<dim3(32), dim3(512), 0, stream>>>(
        Wswz + 2097152, bias + 2048, h0buf + cur * 65536, (const int*)nullptr, t,
        h1buf + prev * 65536, c1, h1buf + cur * 65536,
        (const short*)nullptr, (const short*)nullptr,
        (const float*)nullptr, (const float*)nullptr, (const float*)nullptr, (float*)nullptr);
  }
  proj_last_kernel<<<dim3(4), dim3(512), 0, stream>>>(
      h1buf + 65536, pWswz, lng, lnb, pb, out);
}